// Round 10
// baseline (236.330 us; speedup 1.0000x reference)
//
#include <hip/hip_runtime.h>
#include <cstdint>
#include <cstddef>

#define L_ 256
#define C_ 128
#define H_ 4
#define D_ 32
#define NP_ (L_ * L_)

typedef unsigned short u16;
typedef uint32_t u32;
typedef __attribute__((ext_vector_type(8))) short bf16x8;   // 4 VGPRs: MFMA A/B frag
typedef __attribute__((ext_vector_type(4))) float f32x4;    // MFMA C/D frag

__device__ __forceinline__ float bflo(u32 u) { union { u32 i; float f; } v; v.i = u << 16; return v.f; }
__device__ __forceinline__ float bfhi(u32 u) { union { u32 i; float f; } v; v.i = u & 0xffff0000u; return v.f; }
__device__ __forceinline__ float b2f(u16 u) { union { u32 i; float f; } v; v.i = ((u32)u) << 16; return v.f; }
__device__ __forceinline__ u16 f2b(float f) {
    u32 x = __float_as_uint(f);
    return (u16)((x + 0x7fffu + ((x >> 16) & 1u)) >> 16);
}
__device__ __forceinline__ u32 pk2(float lo, float hi) {
    return ((u32)f2b(hi) << 16) | (u32)f2b(lo);
}
__device__ __forceinline__ bf16x8 pack8(float4 a, float4 b) {
    union { u32 u[4]; bf16x8 v; } r;
    r.u[0] = pk2(a.x, a.y); r.u[1] = pk2(a.z, a.w);
    r.u[2] = pk2(b.x, b.y); r.u[3] = pk2(b.z, b.w);
    return r.v;
}

// ---------------------------------------------------------------------------
// Kernel 0: weight prep. Wt[mat][n][c] bf16 = W[c][n],
// mat = {Wq*LOG2E/sqrt(D), Wk, Wv, Wo, Wg}; WbT[h][c] = Wbias[c][h]*LOG2E.
// ---------------------------------------------------------------------------
__global__ __launch_bounds__(256) void k_prep(
    const float* __restrict__ Wq, const float* __restrict__ Wk, const float* __restrict__ Wv,
    const float* __restrict__ Wo, const float* __restrict__ Wg,
    const float* __restrict__ Wbias, u16* __restrict__ Wt, float* __restrict__ WbT)
{
    __shared__ float tile[64][65];
    const int b = blockIdx.x, t = threadIdx.x;
    if (b < 20) {
        const int mat = b >> 2, tl = b & 3, tr = tl >> 1, tc = tl & 1;
        const float* W = (mat == 0) ? Wq : (mat == 1) ? Wk : (mat == 2) ? Wv : (mat == 3) ? Wo : Wg;
        const float s = (mat == 0) ? 0.2550680544705824f : 1.f;   // LOG2E/sqrt(32)
        const int rlo = t >> 6, col = t & 63;
        #pragma unroll
        for (int m = 0; m < 16; ++m) {
            int row = m * 4 + rlo;
            tile[row][col] = W[(size_t)(tr * 64 + row) * C_ + tc * 64 + col];
        }
        __syncthreads();
        #pragma unroll
        for (int m = 0; m < 16; ++m) {
            int n = tc * 64 + m * 4 + rlo;
            int c = tr * 64 + col;
            Wt[mat * 16384 + n * C_ + c] = f2b(tile[col][m * 4 + rlo] * s);
        }
    } else {
        #pragma unroll
        for (int m = 0; m < 2; ++m) {
            int idx = m * 256 + t;
            int h = idx >> 7, c = idx & 127;
            WbT[h * C_ + c] = Wbias[c * H_ + h] * 1.4426950408889634f;
        }
    }
}

// ---------------------------------------------------------------------------
// Kernel 1: LayerNorm + Q/K/V + bias projection -- 2-CHUNK PIPELINED.
// Round-10 theory: lnmm has been ~52 us since round 3 with all pipes idle and
// occupancy-insensitive duration (round-4 experiment) -> TLP exhausted,
// lockstepped phases can't hide the pair-load latency. Fix = ILP across
// chunks: block owns 128 rows as 2x64; ALL 16 pair loads issue up front
// (A then B -> consumer of A waits at vmcnt(8), B stays in flight across the
// whole A-phase ~2.5K cyc). Chunk body = round-3/9 proven code verbatim.
// Grid 512 (2 blocks/CU); waves_per_eu(2,2) -> 256-VGPR budget (xvB adds
// ~32 regs; no spill possible under the budget).
// ---------------------------------------------------------------------------
__device__ __forceinline__ void lnmm_chunk(
    const float4* xv, int p0, int t, u16 (*zsh)[136],
    const float* __restrict__ ln_g, const float* __restrict__ ln_b,
    const u16* __restrict__ Wt, const float* __restrict__ WbT,
    u16* __restrict__ qh, u16* __restrict__ kh, u16* __restrict__ vh,
    u16* __restrict__ biasN)
{
    const int row = t >> 2, seg = t & 3;

    float sum = 0.f, ss = 0.f;
    #pragma unroll
    for (int i = 0; i < 8; ++i) {
        float4 x = xv[i];
        sum += x.x + x.y + x.z + x.w;
        ss  += x.x * x.x + x.y * x.y + x.z * x.z + x.w * x.w;
    }
    sum += __shfl_xor(sum, 1); sum += __shfl_xor(sum, 2);
    ss  += __shfl_xor(ss, 1);  ss  += __shfl_xor(ss, 2);
    float mu  = sum * (1.0f / C_);
    float var = ss * (1.0f / C_) - mu * mu;
    float rs  = rsqrtf(fmaxf(var, 0.f) + 1e-5f);

    #pragma unroll
    for (int i = 0; i < 8; ++i) {
        int c = (seg + 4 * i) * 4;
        float4 g4 = *(const float4*)(ln_g + c);
        float4 b4 = *(const float4*)(ln_b + c);
        float4 x  = xv[i];
        float z0 = (x.x - mu) * rs * g4.x + b4.x;
        float z1 = (x.y - mu) * rs * g4.y + b4.y;
        float z2 = (x.z - mu) * rs * g4.z + b4.z;
        float z3 = (x.w - mu) * rs * g4.w + b4.w;
        *(u32*)&zsh[row][c]     = pk2(z0, z1);
        *(u32*)&zsh[row][c + 2] = pk2(z2, z3);
    }
    __syncthreads();

    const int w    = t >> 6;
    const int l15  = t & 15;
    const int quad = (t >> 4) & 3;

    bf16x8 zf[4][4];
    #pragma unroll
    for (int jt = 0; jt < 4; ++jt)
        #pragma unroll
        for (int kc = 0; kc < 4; ++kc)
            zf[jt][kc] = *(const bf16x8*)&zsh[jt * 16 + l15][kc * 32 + quad * 8];

    #pragma unroll
    for (int k = 0; k < 6; ++k) {
        const int tt = w * 6 + k;
        const int mat = tt >> 3, mt = tt & 7;
        f32x4 acc0 = {0.f,0.f,0.f,0.f}, acc1 = acc0, acc2 = acc0, acc3 = acc0;
        #pragma unroll
        for (int kc = 0; kc < 4; ++kc) {
            bf16x8 af = *(const bf16x8*)(Wt + (size_t)tt * 2048 + (size_t)l15 * 128 + kc * 32 + quad * 8);
            acc0 = __builtin_amdgcn_mfma_f32_16x16x32_bf16(af, zf[0][kc], acc0, 0, 0, 0);
            acc1 = __builtin_amdgcn_mfma_f32_16x16x32_bf16(af, zf[1][kc], acc1, 0, 0, 0);
            acc2 = __builtin_amdgcn_mfma_f32_16x16x32_bf16(af, zf[2][kc], acc2, 0, 0, 0);
            acc3 = __builtin_amdgcn_mfma_f32_16x16x32_bf16(af, zf[3][kc], acc3, 0, 0, 0);
        }
        u16* dst = (mat == 0) ? qh : (mat == 1) ? kh : vh;
        const int hh = mt >> 1;
        const int cb = (mt & 1) * 16 + quad * 4;
        f32x4 accs[4] = {acc0, acc1, acc2, acc3};
        #pragma unroll
        for (int jt = 0; jt < 4; ++jt) {
            const int p = p0 + jt * 16 + l15;
            *(uint2*)(dst + ((size_t)hh * NP_ + p) * D_ + cb) =
                make_uint2(pk2(accs[jt][0], accs[jt][1]), pk2(accs[jt][2], accs[jt][3]));
        }
    }

    // bias projection: thread (row, h=seg); biasN[h][p] bf16, LOG2E-prescaled
    {
        float a = 0.f;
        #pragma unroll
        for (int c8 = 0; c8 < C_; c8 += 8) {
            uint4 zz = *(const uint4*)&zsh[row][c8];
            float4 wb0 = *(const float4*)(WbT + seg * C_ + c8);
            float4 wb1 = *(const float4*)(WbT + seg * C_ + c8 + 4);
            a += bflo(zz.x) * wb0.x + bfhi(zz.x) * wb0.y
               + bflo(zz.y) * wb0.z + bfhi(zz.y) * wb0.w
               + bflo(zz.z) * wb1.x + bfhi(zz.z) * wb1.y
               + bflo(zz.w) * wb1.z + bfhi(zz.w) * wb1.w;
        }
        const int p = p0 + row;
        biasN[(size_t)seg * NP_ + p] = f2b(a);
    }
}

__global__ __launch_bounds__(256)
__attribute__((amdgpu_waves_per_eu(2, 2)))
void k_lnmm(
    const float* __restrict__ pair, const float* __restrict__ ln_g, const float* __restrict__ ln_b,
    const u16* __restrict__ Wt, const float* __restrict__ WbT,
    u16* __restrict__ qh, u16* __restrict__ kh, u16* __restrict__ vh,
    u16* __restrict__ biasN)
{
    __shared__ u16 zsh[64][136];

    const int t   = threadIdx.x;
    const int row = t >> 2, seg = t & 3;
    const int p0  = blockIdx.x * 128;

    // issue ALL chunk-A loads, then ALL chunk-B loads: A's consumer waits at
    // vmcnt(8); B's 8 loads remain in flight across the entire A phase.
    float4 xvA[8], xvB[8];
    #pragma unroll
    for (int i = 0; i < 8; ++i) {
        int c = (seg + 4 * i) * 4;
        xvA[i] = *(const float4*)(pair + (size_t)(p0 + row) * C_ + c);
    }
    #pragma unroll
    for (int i = 0; i < 8; ++i) {
        int c = (seg + 4 * i) * 4;
        xvB[i] = *(const float4*)(pair + (size_t)(p0 + 64 + row) * C_ + c);
    }

    lnmm_chunk(xvA, p0, t, zsh, ln_g, ln_b, Wt, WbT, qh, kh, vh, biasN);
    __syncthreads();   // zsh WAR: chunk B rewrites it after A's bias reads
    lnmm_chunk(xvB, p0 + 64, t, zsh, ln_g, ln_b, Wt, WbT, qh, kh, vh, biasN);
}

// ---------------------------------------------------------------------------
// Kernel 2: attention + output projection merged (round-9 verbatim, 72 us).
// bias bf16 loads; Wo/Wg staged once into the attn-dead LDS region.
// ---------------------------------------------------------------------------
__global__ __launch_bounds__(1024)
__attribute__((amdgpu_waves_per_eu(4, 4)))
void k_ao(
    const u16* __restrict__ qh, const u16* __restrict__ kh, const u16* __restrict__ vh,
    const u16* __restrict__ biasN, const float* __restrict__ pair,
    const u16* __restrict__ Wt, const float* __restrict__ bo,
    const float* __restrict__ bg, float* __restrict__ out)
{
    __shared__ __align__(16) char shA[88064];   // attn: Vsh+Psh; out: WoSh+WgSh
    __shared__ u16 ao_sh[256 * 136];            // attn out [row][h*32+d]

    u16* Vsh = reinterpret_cast<u16*>(shA);                     // 4*32*264 u16
    auto Psh = reinterpret_cast<u16(*)[16][40]>(shA + 67584);   // [16][16][40]

    const int t = threadIdx.x;
    const int i = blockIdx.x;
    const int wave = t >> 6;              // 0..15
    const int h    = wave >> 2;           // head 0..3
    const int ww   = wave & 3;            // j-quarter
    const int l15  = t & 15;
    const int quad = (t >> 4) & 3;
    const int jbase = ww * 64;

    const u16* Kg = kh + ((size_t)h * NP_ + i * L_) * D_;
    const u16* Qg = qh + ((size_t)h * NP_ + i * L_) * D_;

    // ---- stage V transposed for ALL 4 heads ----
    #pragma unroll
    for (int jj = 0; jj < 4; ++jj) {
        int idx = t + jj * 1024;
        int hs = idx >> 10, rem = idx & 1023;
        int r = rem >> 2, sg = rem & 3;
        const u16* Vg = vh + ((size_t)hs * NP_ + i * L_) * D_;
        union { uint4 q; u16 s[8]; } u;
        u.q = *(const uint4*)(Vg + r * D_ + sg * 8);
        #pragma unroll
        for (int m = 0; m < 8; ++m) Vsh[hs * 8448 + (sg * 8 + m) * 264 + r] = u.s[m];
    }

    // ---- Q B-frags (4 j-tiles per wave) ----
    bf16x8 qf[4];
    #pragma unroll
    for (int jt = 0; jt < 4; ++jt)
        qf[jt] = *(const bf16x8*)(Qg + (size_t)(jbase + jt * 16 + l15) * D_ + quad * 8);

    __syncthreads();

    const f32x4 z4 = {0.f, 0.f, 0.f, 0.f};
    f32x4 oacc[4][2], osum[4];
    #pragma unroll
    for (int jt = 0; jt < 4; ++jt) {
        oacc[jt][0] = z4; oacc[jt][1] = z4; osum[jt] = z4;
    }

    bf16x8 onesb;
    { union { u32 u[4]; bf16x8 v; } ob;
      ob.u[0] = ob.u[1] = ob.u[2] = ob.u[3] = 0x3F803F80u; onesb = ob.v; }

    const u16* bN = biasN + (size_t)h * NP_;   // [j][k] bf16, LOG2E-scaled
    const u16* Vs = Vsh + h * 8448;

    bf16x8 kb0 = *(const bf16x8*)(Kg + (size_t)l15 * D_ + quad * 8);
    bf16x8 kb1 = *(const bf16x8*)(Kg + (size_t)(16 + l15) * D_ + quad * 8);

    for (int kc = 0; kc < 8; ++kc) {
        bf16x8 nb0, nb1;
        if (kc < 7) {
            nb0 = *(const bf16x8*)(Kg + (size_t)((kc + 1) * 32 + l15) * D_ + quad * 8);
            nb1 = *(const bf16x8*)(Kg + (size_t)((kc + 1) * 32 + 16 + l15) * D_ + quad * 8);
        }
        bf16x8 vb0 = *(const bf16x8*)&Vs[l15 * 264 + kc * 32 + quad * 8];
        bf16x8 vb1 = *(const bf16x8*)&Vs[(16 + l15) * 264 + kc * 32 + quad * 8];

        #pragma unroll
        for (int jt = 0; jt < 4; ++jt) {
            f32x4 s0 = __builtin_amdgcn_mfma_f32_16x16x32_bf16(kb0, qf[jt], z4, 0, 0, 0);
            f32x4 s1 = __builtin_amdgcn_mfma_f32_16x16x32_bf16(kb1, qf[jt], z4, 0, 0, 0);

            const u16* bp = bN + (size_t)(jbase + jt * 16 + l15) * L_ + kc * 32 + quad * 4;
            uint2 bv0 = *(const uint2*)bp;          // bias[j][k..k+3] bf16
            uint2 bv1 = *(const uint2*)(bp + 16);   // bias[j][k+16..k+19]
            const u16* b0p = (const u16*)&bv0;
            const u16* b1p = (const u16*)&bv1;

            float e0[4], e1[4];
            #pragma unroll
            for (int r = 0; r < 4; ++r) {
                e0[r] = __builtin_amdgcn_exp2f(s0[r] + b2f(b0p[r]));
                e1[r] = __builtin_amdgcn_exp2f(s1[r] + b2f(b1p[r]));
            }

            u32 w0, w1, w2, w3;
            asm("v_cvt_pk_bf16_f32 %0, %1, %2" : "=v"(w0) : "v"(e0[0]), "v"(e0[1]));
            asm("v_cvt_pk_bf16_f32 %0, %1, %2" : "=v"(w1) : "v"(e0[2]), "v"(e0[3]));
            asm("v_cvt_pk_bf16_f32 %0, %1, %2" : "=v"(w2) : "v"(e1[0]), "v"(e1[1]));
            asm("v_cvt_pk_bf16_f32 %0, %1, %2" : "=v"(w3) : "v"(e1[2]), "v"(e1[3]));
            *(uint2*)&Psh[wave][l15][quad * 4]      = make_uint2(w0, w1);
            *(uint2*)&Psh[wave][l15][16 + quad * 4] = make_uint2(w2, w3);

            bf16x8 pa = *(const bf16x8*)&Psh[wave][l15][quad * 8];
            oacc[jt][0] = __builtin_amdgcn_mfma_f32_16x16x32_bf16(pa, vb0,   oacc[jt][0], 0, 0, 0);
            oacc[jt][1] = __builtin_amdgcn_mfma_f32_16x16x32_bf16(pa, vb1,   oacc[jt][1], 0, 0, 0);
            osum[jt]    = __builtin_amdgcn_mfma_f32_16x16x32_bf16(pa, onesb, osum[jt],    0, 0, 0);
        }
        kb0 = nb0; kb1 = nb1;
    }

    // ---- normalize + write to LDS ao_sh[row][h*32 + d] ----
    #pragma unroll
    for (int jt = 0; jt < 4; ++jt) {
        #pragma unroll
        for (int r = 0; r < 4; ++r) {
            float rn = 1.f / osum[jt][r];
            int prow = jbase + jt * 16 + quad * 4 + r;          // 0..255
            ao_sh[prow * 136 + h * 32 + l15]      = f2b(oacc[jt][0][r] * rn);
            ao_sh[prow * 136 + h * 32 + 16 + l15] = f2b(oacc[jt][1][r] * rn);
        }
    }

    __syncthreads();   // attn done: Vsh/Psh dead, ao_sh complete

    // ---- stage Wo/Wg into the dead attn region, pad-136 stride ----
    u16* WoSh = reinterpret_cast<u16*>(shA);            // [128][136]
    u16* WgSh = WoSh + 128 * 136;                       // [128][136]
    {
        const u16* WoT = Wt + 3 * 16384;
        const u16* WgT = Wt + 4 * 16384;
        #pragma unroll
        for (int m = 0; m < 2; ++m) {
            int idx = t + m * 1024;
            int rw = idx >> 4, cl = (idx & 15) * 8;
            *(uint4*)&WoSh[rw * 136 + cl] = *(const uint4*)(WoT + rw * 128 + cl);
            *(uint4*)&WgSh[rw * 136 + cl] = *(const uint4*)(WgT + rw * 128 + cl);
        }
    }
    __syncthreads();

    // ================= out phase: wave owns 16 rows =================
    const int prow_l = wave * 16 + l15;          // local row 0..255
    const int pg     = i * L_ + prow_l;          // global pair row

    bf16x8 aof[4], pf[4];
    #pragma unroll
    for (int kc = 0; kc < 4; ++kc) {
        aof[kc] = *(const bf16x8*)&ao_sh[prow_l * 136 + kc * 32 + quad * 8];
        const float* pp = pair + (size_t)pg * C_ + kc * 32 + quad * 8;
        pf[kc] = pack8(*(const float4*)pp, *(const float4*)(pp + 4));
    }

    #pragma unroll
    for (int nt = 0; nt < 8; ++nt) {
        f32x4 accO = {0.f,0.f,0.f,0.f}, accG = accO;
        #pragma unroll
        for (int kc = 0; kc < 4; ++kc) {
            bf16x8 awo = *(const bf16x8*)&WoSh[(nt * 16 + l15) * 136 + kc * 32 + quad * 8];
            bf16x8 awg = *(const bf16x8*)&WgSh[(nt * 16 + l15) * 136 + kc * 32 + quad * 8];
            accO = __builtin_amdgcn_mfma_f32_16x16x32_bf16(awo, aof[kc], accO, 0, 0, 0);
            accG = __builtin_amdgcn_mfma_f32_16x16x32_bf16(awg, pf[kc],  accG, 0, 0, 0);
        }
        const int ch = nt * 16 + quad * 4;
        float4 bo4 = *(const float4*)(bo + ch);
        float4 bg4 = *(const float4*)(bg + ch);
        float4 pr  = *(const float4*)(pair + (size_t)pg * C_ + ch);
        float4 r;
        r.x = pr.x + (1.f / (1.f + __expf(-(accG[0] + bg4.x)))) * (accO[0] + bo4.x);
        r.y = pr.y + (1.f / (1.f + __expf(-(accG[1] + bg4.y)))) * (accO[1] + bo4.y);
        r.z = pr.z + (1.f / (1.f + __expf(-(accG[2] + bg4.z)))) * (accO[2] + bo4.z);
        r.w = pr.w + (1.f / (1.f + __expf(-(accG[3] + bg4.w)))) * (accO[3] + bo4.w);
        *(float4*)(out + (size_t)pg * C_ + ch) = r;
    }
}

// ---------------------------------------------------------------------------
// Workspace (~51 MB):
//   [0, 0.5 MB)    biasN bf16 [H][j][k]   (natural layout, LOG2E-prescaled)
//   [+,  +16.8MB)  qh bf16 [H][NP][32]
//   [+,  +16.8MB)  kh
//   [+,  +16.8MB)  vh
//   [+,  +160K)    Wt bf16 [5][128][128]
//   [+,  +2K)      WbT fp32 [4][128]
// ---------------------------------------------------------------------------
extern "C" void kernel_launch(void* const* d_in, const int* in_sizes, int n_in,
                              void* d_out, int out_size, void* d_ws, size_t ws_size,
                              hipStream_t stream) {
    const float* pair  = (const float*)d_in[0];
    const float* ln_g  = (const float*)d_in[1];
    const float* ln_b  = (const float*)d_in[2];
    const float* Wq    = (const float*)d_in[3];
    const float* Wk    = (const float*)d_in[4];
    const float* Wv    = (const float*)d_in[5];
    const float* Wbias = (const float*)d_in[6];
    const float* Wo    = (const float*)d_in[7];
    const float* bo    = (const float*)d_in[8];
    const float* Wg    = (const float*)d_in[9];
    const float* bg    = (const float*)d_in[10];
    float* out = (float*)d_out;

    u16* biasN = (u16*)d_ws;                          // 0.5 MB bf16
    u16* qh = biasN + (size_t)H_ * NP_;
    u16* kh = qh + (size_t)NP_ * C_;
    u16* vh = kh + (size_t)NP_ * C_;
    u16* Wt = vh + (size_t)NP_ * C_;
    float* WbT = (float*)(Wt + 5 * 16384);

    k_prep<<<21, 256, 0, stream>>>(Wq, Wk, Wv, Wo, Wg, Wbias, Wt, WbT);
    k_lnmm<<<NP_ / 128, 256, 0, stream>>>(pair, ln_g, ln_b, Wt, WbT, qh, kh, vh, biasN);
    k_ao<<<L_, 1024, 0, stream>>>(qh, kh, vh, biasN, pair, Wt, bo, bg, out);
}

// Round 11
// 205.516 us; speedup vs baseline: 1.1499x; 1.1499x over previous
//
#include <hip/hip_runtime.h>
#include <cstdint>
#include <cstddef>

#define L_ 256
#define C_ 128
#define H_ 4
#define D_ 32
#define NP_ (L_ * L_)

typedef unsigned short u16;
typedef uint32_t u32;
typedef __attribute__((ext_vector_type(8))) short bf16x8;   // 4 VGPRs: MFMA A/B frag
typedef __attribute__((ext_vector_type(4))) float f32x4;    // MFMA C/D frag

__device__ __forceinline__ float bflo(u32 u) { union { u32 i; float f; } v; v.i = u << 16; return v.f; }
__device__ __forceinline__ float bfhi(u32 u) { union { u32 i; float f; } v; v.i = u & 0xffff0000u; return v.f; }
__device__ __forceinline__ float b2f(u16 u) { union { u32 i; float f; } v; v.i = ((u32)u) << 16; return v.f; }
__device__ __forceinline__ u16 f2b(float f) {
    u32 x = __float_as_uint(f);
    return (u16)((x + 0x7fffu + ((x >> 16) & 1u)) >> 16);
}
__device__ __forceinline__ u32 pk2(float lo, float hi) {
    return ((u32)f2b(hi) << 16) | (u32)f2b(lo);
}
__device__ __forceinline__ bf16x8 pack8(float4 a, float4 b) {
    union { u32 u[4]; bf16x8 v; } r;
    r.u[0] = pk2(a.x, a.y); r.u[1] = pk2(a.z, a.w);
    r.u[2] = pk2(b.x, b.y); r.u[3] = pk2(b.z, b.w);
    return r.v;
}

// ---------------------------------------------------------------------------
// Kernel 0: weight prep. Wt[mat][n][c] bf16 = W[c][n],
// mat = {Wq*LOG2E/sqrt(D), Wk, Wv, Wo, Wg}; WbT[h][c] = Wbias[c][h]*LOG2E.
// ---------------------------------------------------------------------------
__global__ __launch_bounds__(256) void k_prep(
    const float* __restrict__ Wq, const float* __restrict__ Wk, const float* __restrict__ Wv,
    const float* __restrict__ Wo, const float* __restrict__ Wg,
    const float* __restrict__ Wbias, u16* __restrict__ Wt, float* __restrict__ WbT)
{
    __shared__ float tile[64][65];
    const int b = blockIdx.x, t = threadIdx.x;
    if (b < 20) {
        const int mat = b >> 2, tl = b & 3, tr = tl >> 1, tc = tl & 1;
        const float* W = (mat == 0) ? Wq : (mat == 1) ? Wk : (mat == 2) ? Wv : (mat == 3) ? Wo : Wg;
        const float s = (mat == 0) ? 0.2550680544705824f : 1.f;   // LOG2E/sqrt(32)
        const int rlo = t >> 6, col = t & 63;
        #pragma unroll
        for (int m = 0; m < 16; ++m) {
            int row = m * 4 + rlo;
            tile[row][col] = W[(size_t)(tr * 64 + row) * C_ + tc * 64 + col];
        }
        __syncthreads();
        #pragma unroll
        for (int m = 0; m < 16; ++m) {
            int n = tc * 64 + m * 4 + rlo;
            int c = tr * 64 + col;
            Wt[mat * 16384 + n * C_ + c] = f2b(tile[col][m * 4 + rlo] * s);
        }
    } else {
        #pragma unroll
        for (int m = 0; m < 2; ++m) {
            int idx = m * 256 + t;
            int h = idx >> 7, c = idx & 127;
            WbT[h * C_ + c] = Wbias[c * H_ + h] * 1.4426950408889634f;
        }
    }
}

// ---------------------------------------------------------------------------
// Kernel 1: LayerNorm + Q/K/V + bias projection -- 4x32-row chunks per block,
// software-pipelined prefetch. Round-10 failed because chunk arrays passed
// as a POINTER to a helper defeated register promotion (scratch, 130 MB
// writes). Round-11: everything inline, #pragma unroll makes xv/xvN static
// (ping-pong SSA regs). 32-row body = round-4 verified (48 VGPR standalone);
// peak live set ~80-100 VGPR -> plain launch_bounds(256), NO waves_per_eu.
// Prefetch for chunk c+1 issues after chunk c's post-LN barrier: ~2K cycles
// of MFMA/stores cover the ~900-cy HBM latency of the next chunk's loads.
// Grid 512. Spill tripwire: WRITE >> 52 MB.
// ---------------------------------------------------------------------------
__global__ __launch_bounds__(256) void k_lnmm(
    const float* __restrict__ pair, const float* __restrict__ ln_g, const float* __restrict__ ln_b,
    const u16* __restrict__ Wt, const float* __restrict__ WbT,
    u16* __restrict__ qh, u16* __restrict__ kh, u16* __restrict__ vh,
    u16* __restrict__ biasN)
{
    __shared__ u16 zsh[32][136];      // one 32-row chunk, stride 272 B

    const int t    = threadIdx.x;
    const int p0   = blockIdx.x * 128;
    const int row  = t >> 3, seg = t & 7;     // LN: 8 lanes/row, 32 rows
    const int w    = t >> 6;
    const int l15  = t & 15;
    const int quad = (t >> 4) & 3;

    float4 xv[4], xvN[4];

    // prologue: chunk 0 loads
    #pragma unroll
    for (int i = 0; i < 4; ++i) {
        int c = (seg + 8 * i) * 4;
        xv[i] = *(const float4*)(pair + (size_t)(p0 + row) * C_ + c);
    }

    #pragma unroll
    for (int chk = 0; chk < 4; ++chk) {
        const int pc = p0 + chk * 32;

        // ---- LN phase (consumes xv) ----
        float sum = 0.f, ss = 0.f;
        #pragma unroll
        for (int i = 0; i < 4; ++i) {
            float4 x = xv[i];
            sum += x.x + x.y + x.z + x.w;
            ss  += x.x * x.x + x.y * x.y + x.z * x.z + x.w * x.w;
        }
        sum += __shfl_xor(sum, 1); sum += __shfl_xor(sum, 2); sum += __shfl_xor(sum, 4);
        ss  += __shfl_xor(ss, 1);  ss  += __shfl_xor(ss, 2);  ss  += __shfl_xor(ss, 4);
        float mu  = sum * (1.0f / C_);
        float var = ss * (1.0f / C_) - mu * mu;
        float rs  = rsqrtf(fmaxf(var, 0.f) + 1e-5f);

        #pragma unroll
        for (int i = 0; i < 4; ++i) {
            int c = (seg + 8 * i) * 4;
            float4 g4 = *(const float4*)(ln_g + c);
            float4 b4 = *(const float4*)(ln_b + c);
            float4 x  = xv[i];
            float z0 = (x.x - mu) * rs * g4.x + b4.x;
            float z1 = (x.y - mu) * rs * g4.y + b4.y;
            float z2 = (x.z - mu) * rs * g4.z + b4.z;
            float z3 = (x.w - mu) * rs * g4.w + b4.w;
            *(u32*)&zsh[row][c]     = pk2(z0, z1);
            *(u32*)&zsh[row][c + 2] = pk2(z2, z3);
        }
        __syncthreads();

        // ---- prefetch next chunk (xv regs now dead; loads fly over MFMA) ----
        if (chk < 3) {
            #pragma unroll
            for (int i = 0; i < 4; ++i) {
                int c = (seg + 8 * i) * 4;
                xvN[i] = *(const float4*)(pair + (size_t)(pc + 32 + row) * C_ + c);
            }
        }

        // ---- MFMA phase (round-4 32-row body) ----
        bf16x8 zf[2][4];
        #pragma unroll
        for (int jt = 0; jt < 2; ++jt)
            #pragma unroll
            for (int kc = 0; kc < 4; ++kc)
                zf[jt][kc] = *(const bf16x8*)&zsh[jt * 16 + l15][kc * 32 + quad * 8];

        #pragma unroll
        for (int k = 0; k < 6; ++k) {
            const int tt = w * 6 + k;
            const int mat = tt >> 3, mt = tt & 7;
            f32x4 acc0 = {0.f,0.f,0.f,0.f}, acc1 = acc0;
            #pragma unroll
            for (int kc = 0; kc < 4; ++kc) {
                bf16x8 af = *(const bf16x8*)(Wt + (size_t)tt * 2048 + (size_t)l15 * 128 + kc * 32 + quad * 8);
                acc0 = __builtin_amdgcn_mfma_f32_16x16x32_bf16(af, zf[0][kc], acc0, 0, 0, 0);
                acc1 = __builtin_amdgcn_mfma_f32_16x16x32_bf16(af, zf[1][kc], acc1, 0, 0, 0);
            }
            u16* dst = (mat == 0) ? qh : (mat == 1) ? kh : vh;
            const int hh = mt >> 1;
            const int cb = (mt & 1) * 16 + quad * 4;
            f32x4 accs[2] = {acc0, acc1};
            #pragma unroll
            for (int jt = 0; jt < 2; ++jt) {
                const int p = pc + jt * 16 + l15;
                *(uint2*)(dst + ((size_t)hh * NP_ + p) * D_ + cb) =
                    make_uint2(pk2(accs[jt][0], accs[jt][1]), pk2(accs[jt][2], accs[jt][3]));
            }
        }

        // ---- bias projection: threads t<128: (row2, h=seg2) ----
        if (t < 128) {
            const int row2 = t >> 2, seg2 = t & 3;
            float a = 0.f;
            #pragma unroll
            for (int c8 = 0; c8 < C_; c8 += 8) {
                uint4 zz = *(const uint4*)&zsh[row2][c8];
                float4 wb0 = *(const float4*)(WbT + seg2 * C_ + c8);
                float4 wb1 = *(const float4*)(WbT + seg2 * C_ + c8 + 4);
                a += bflo(zz.x) * wb0.x + bfhi(zz.x) * wb0.y
                   + bflo(zz.y) * wb0.z + bfhi(zz.y) * wb0.w
                   + bflo(zz.z) * wb1.x + bfhi(zz.z) * wb1.y
                   + bflo(zz.w) * wb1.z + bfhi(zz.w) * wb1.w;
            }
            const int p = pc + row2;
            biasN[(size_t)seg2 * NP_ + p] = f2b(a);
        }
        __syncthreads();   // WAR: next LN rewrites zsh

        // ping-pong (unrolled -> pure SSA rename, no scratch)
        if (chk < 3) {
            #pragma unroll
            for (int i = 0; i < 4; ++i) xv[i] = xvN[i];
        }
    }
}

// ---------------------------------------------------------------------------
// Kernel 2: attention + output projection merged (round-9 verbatim, 72 us).
// bias bf16 loads; Wo/Wg staged once into the attn-dead LDS region.
// ---------------------------------------------------------------------------
__global__ __launch_bounds__(1024)
__attribute__((amdgpu_waves_per_eu(4, 4)))
void k_ao(
    const u16* __restrict__ qh, const u16* __restrict__ kh, const u16* __restrict__ vh,
    const u16* __restrict__ biasN, const float* __restrict__ pair,
    const u16* __restrict__ Wt, const float* __restrict__ bo,
    const float* __restrict__ bg, float* __restrict__ out)
{
    __shared__ __align__(16) char shA[88064];   // attn: Vsh+Psh; out: WoSh+WgSh
    __shared__ u16 ao_sh[256 * 136];            // attn out [row][h*32+d]

    u16* Vsh = reinterpret_cast<u16*>(shA);                     // 4*32*264 u16
    auto Psh = reinterpret_cast<u16(*)[16][40]>(shA + 67584);   // [16][16][40]

    const int t = threadIdx.x;
    const int i = blockIdx.x;
    const int wave = t >> 6;              // 0..15
    const int h    = wave >> 2;           // head 0..3
    const int ww   = wave & 3;            // j-quarter
    const int l15  = t & 15;
    const int quad = (t >> 4) & 3;
    const int jbase = ww * 64;

    const u16* Kg = kh + ((size_t)h * NP_ + i * L_) * D_;
    const u16* Qg = qh + ((size_t)h * NP_ + i * L_) * D_;

    // ---- stage V transposed for ALL 4 heads ----
    #pragma unroll
    for (int jj = 0; jj < 4; ++jj) {
        int idx = t + jj * 1024;
        int hs = idx >> 10, rem = idx & 1023;
        int r = rem >> 2, sg = rem & 3;
        const u16* Vg = vh + ((size_t)hs * NP_ + i * L_) * D_;
        union { uint4 q; u16 s[8]; } u;
        u.q = *(const uint4*)(Vg + r * D_ + sg * 8);
        #pragma unroll
        for (int m = 0; m < 8; ++m) Vsh[hs * 8448 + (sg * 8 + m) * 264 + r] = u.s[m];
    }

    // ---- Q B-frags (4 j-tiles per wave) ----
    bf16x8 qf[4];
    #pragma unroll
    for (int jt = 0; jt < 4; ++jt)
        qf[jt] = *(const bf16x8*)(Qg + (size_t)(jbase + jt * 16 + l15) * D_ + quad * 8);

    __syncthreads();

    const f32x4 z4 = {0.f, 0.f, 0.f, 0.f};
    f32x4 oacc[4][2], osum[4];
    #pragma unroll
    for (int jt = 0; jt < 4; ++jt) {
        oacc[jt][0] = z4; oacc[jt][1] = z4; osum[jt] = z4;
    }

    bf16x8 onesb;
    { union { u32 u[4]; bf16x8 v; } ob;
      ob.u[0] = ob.u[1] = ob.u[2] = ob.u[3] = 0x3F803F80u; onesb = ob.v; }

    const u16* bN = biasN + (size_t)h * NP_;   // [j][k] bf16, LOG2E-scaled
    const u16* Vs = Vsh + h * 8448;

    bf16x8 kb0 = *(const bf16x8*)(Kg + (size_t)l15 * D_ + quad * 8);
    bf16x8 kb1 = *(const bf16x8*)(Kg + (size_t)(16 + l15) * D_ + quad * 8);

    for (int kc = 0; kc < 8; ++kc) {
        bf16x8 nb0, nb1;
        if (kc < 7) {
            nb0 = *(const bf16x8*)(Kg + (size_t)((kc + 1) * 32 + l15) * D_ + quad * 8);
            nb1 = *(const bf16x8*)(Kg + (size_t)((kc + 1) * 32 + 16 + l15) * D_ + quad * 8);
        }
        bf16x8 vb0 = *(const bf16x8*)&Vs[l15 * 264 + kc * 32 + quad * 8];
        bf16x8 vb1 = *(const bf16x8*)&Vs[(16 + l15) * 264 + kc * 32 + quad * 8];

        #pragma unroll
        for (int jt = 0; jt < 4; ++jt) {
            f32x4 s0 = __builtin_amdgcn_mfma_f32_16x16x32_bf16(kb0, qf[jt], z4, 0, 0, 0);
            f32x4 s1 = __builtin_amdgcn_mfma_f32_16x16x32_bf16(kb1, qf[jt], z4, 0, 0, 0);

            const u16* bp = bN + (size_t)(jbase + jt * 16 + l15) * L_ + kc * 32 + quad * 4;
            uint2 bv0 = *(const uint2*)bp;          // bias[j][k..k+3] bf16
            uint2 bv1 = *(const uint2*)(bp + 16);   // bias[j][k+16..k+19]
            const u16* b0p = (const u16*)&bv0;
            const u16* b1p = (const u16*)&bv1;

            float e0[4], e1[4];
            #pragma unroll
            for (int r = 0; r < 4; ++r) {
                e0[r] = __builtin_amdgcn_exp2f(s0[r] + b2f(b0p[r]));
                e1[r] = __builtin_amdgcn_exp2f(s1[r] + b2f(b1p[r]));
            }

            u32 w0, w1, w2, w3;
            asm("v_cvt_pk_bf16_f32 %0, %1, %2" : "=v"(w0) : "v"(e0[0]), "v"(e0[1]));
            asm("v_cvt_pk_bf16_f32 %0, %1, %2" : "=v"(w1) : "v"(e0[2]), "v"(e0[3]));
            asm("v_cvt_pk_bf16_f32 %0, %1, %2" : "=v"(w2) : "v"(e1[0]), "v"(e1[1]));
            asm("v_cvt_pk_bf16_f32 %0, %1, %2" : "=v"(w3) : "v"(e1[2]), "v"(e1[3]));
            *(uint2*)&Psh[wave][l15][quad * 4]      = make_uint2(w0, w1);
            *(uint2*)&Psh[wave][l15][16 + quad * 4] = make_uint2(w2, w3);

            bf16x8 pa = *(const bf16x8*)&Psh[wave][l15][quad * 8];
            oacc[jt][0] = __builtin_amdgcn_mfma_f32_16x16x32_bf16(pa, vb0,   oacc[jt][0], 0, 0, 0);
            oacc[jt][1] = __builtin_amdgcn_mfma_f32_16x16x32_bf16(pa, vb1,   oacc[jt][1], 0, 0, 0);
            osum[jt]    = __builtin_amdgcn_mfma_f32_16x16x32_bf16(pa, onesb, osum[jt],    0, 0, 0);
        }
        kb0 = nb0; kb1 = nb1;
    }

    // ---- normalize + write to LDS ao_sh[row][h*32 + d] ----
    #pragma unroll
    for (int jt = 0; jt < 4; ++jt) {
        #pragma unroll
        for (int r = 0; r < 4; ++r) {
            float rn = 1.f / osum[jt][r];
            int prow = jbase + jt * 16 + quad * 4 + r;          // 0..255
            ao_sh[prow * 136 + h * 32 + l15]      = f2b(oacc[jt][0][r] * rn);
            ao_sh[prow * 136 + h * 32 + 16 + l15] = f2b(oacc[jt][1][r] * rn);
        }
    }

    __syncthreads();   // attn done: Vsh/Psh dead, ao_sh complete

    // ---- stage Wo/Wg into the dead attn region, pad-136 stride ----
    u16* WoSh = reinterpret_cast<u16*>(shA);            // [128][136]
    u16* WgSh = WoSh + 128 * 136;                       // [128][136]
    {
        const u16* WoT = Wt + 3 * 16384;
        const u16* WgT = Wt + 4 * 16384;
        #pragma unroll
        for (int m = 0; m < 2; ++m) {
            int idx = t + m * 1024;
            int rw = idx >> 4, cl = (idx & 15) * 8;
            *(uint4*)&WoSh[rw * 136 + cl] = *(const uint4*)(WoT + rw * 128 + cl);
            *(uint4*)&WgSh[rw * 136 + cl] = *(const uint4*)(WgT + rw * 128 + cl);
        }
    }
    __syncthreads();

    // ================= out phase: wave owns 16 rows =================
    const int prow_l = wave * 16 + l15;          // local row 0..255
    const int pg     = i * L_ + prow_l;          // global pair row

    bf16x8 aof[4], pf[4];
    #pragma unroll
    for (int kc = 0; kc < 4; ++kc) {
        aof[kc] = *(const bf16x8*)&ao_sh[prow_l * 136 + kc * 32 + quad * 8];
        const float* pp = pair + (size_t)pg * C_ + kc * 32 + quad * 8;
        pf[kc] = pack8(*(const float4*)pp, *(const float4*)(pp + 4));
    }

    #pragma unroll
    for (int nt = 0; nt < 8; ++nt) {
        f32x4 accO = {0.f,0.f,0.f,0.f}, accG = accO;
        #pragma unroll
        for (int kc = 0; kc < 4; ++kc) {
            bf16x8 awo = *(const bf16x8*)&WoSh[(nt * 16 + l15) * 136 + kc * 32 + quad * 8];
            bf16x8 awg = *(const bf16x8*)&WgSh[(nt * 16 + l15) * 136 + kc * 32 + quad * 8];
            accO = __builtin_amdgcn_mfma_f32_16x16x32_bf16(awo, aof[kc], accO, 0, 0, 0);
            accG = __builtin_amdgcn_mfma_f32_16x16x32_bf16(awg, pf[kc],  accG, 0, 0, 0);
        }
        const int ch = nt * 16 + quad * 4;
        float4 bo4 = *(const float4*)(bo + ch);
        float4 bg4 = *(const float4*)(bg + ch);
        float4 pr  = *(const float4*)(pair + (size_t)pg * C_ + ch);
        float4 r;
        r.x = pr.x + (1.f / (1.f + __expf(-(accG[0] + bg4.x)))) * (accO[0] + bo4.x);
        r.y = pr.y + (1.f / (1.f + __expf(-(accG[1] + bg4.y)))) * (accO[1] + bo4.y);
        r.z = pr.z + (1.f / (1.f + __expf(-(accG[2] + bg4.z)))) * (accO[2] + bo4.z);
        r.w = pr.w + (1.f / (1.f + __expf(-(accG[3] + bg4.w)))) * (accO[3] + bo4.w);
        *(float4*)(out + (size_t)pg * C_ + ch) = r;
    }
}

// ---------------------------------------------------------------------------
// Workspace (~51 MB):
//   [0, 0.5 MB)    biasN bf16 [H][j][k]   (natural layout, LOG2E-prescaled)
//   [+,  +16.8MB)  qh bf16 [H][NP][32]
//   [+,  +16.8MB)  kh
//   [+,  +16.8MB)  vh
//   [+,  +160K)    Wt bf16 [5][128][128]
//   [+,  +2K)      WbT fp32 [4][128]
// ---------------------------------------------------------------------------
extern "C" void kernel_launch(void* const* d_in, const int* in_sizes, int n_in,
                              void* d_out, int out_size, void* d_ws, size_t ws_size,
                              hipStream_t stream) {
    const float* pair  = (const float*)d_in[0];
    const float* ln_g  = (const float*)d_in[1];
    const float* ln_b  = (const float*)d_in[2];
    const float* Wq    = (const float*)d_in[3];
    const float* Wk    = (const float*)d_in[4];
    const float* Wv    = (const float*)d_in[5];
    const float* Wbias = (const float*)d_in[6];
    const float* Wo    = (const float*)d_in[7];
    const float* bo    = (const float*)d_in[8];
    const float* Wg    = (const float*)d_in[9];
    const float* bg    = (const float*)d_in[10];
    float* out = (float*)d_out;

    u16* biasN = (u16*)d_ws;                          // 0.5 MB bf16
    u16* qh = biasN + (size_t)H_ * NP_;
    u16* kh = qh + (size_t)NP_ * C_;
    u16* vh = kh + (size_t)NP_ * C_;
    u16* Wt = vh + (size_t)NP_ * C_;
    float* WbT = (float*)(Wt + 5 * 16384);

    k_prep<<<21, 256, 0, stream>>>(Wq, Wk, Wv, Wo, Wg, Wbias, Wt, WbT);
    k_lnmm<<<NP_ / 128, 256, 0, stream>>>(pair, ln_g, ln_b, Wt, WbT, qh, kh, vh, biasN);
    k_ao<<<L_, 1024, 0, stream>>>(qh, kh, vh, biasN, pair, Wt, bo, bg, out);
}

// Round 12
// 181.945 us; speedup vs baseline: 1.2989x; 1.1295x over previous
//
#include <hip/hip_runtime.h>
#include <cstdint>
#include <cstddef>

#define L_ 256
#define C_ 128
#define H_ 4
#define D_ 32
#define NP_ (L_ * L_)

typedef unsigned short u16;
typedef uint32_t u32;
typedef __attribute__((ext_vector_type(8))) short bf16x8;   // 4 VGPRs: MFMA A/B frag
typedef __attribute__((ext_vector_type(4))) float f32x4;    // MFMA C/D frag

__device__ __forceinline__ float bflo(u32 u) { union { u32 i; float f; } v; v.i = u << 16; return v.f; }
__device__ __forceinline__ float bfhi(u32 u) { union { u32 i; float f; } v; v.i = u & 0xffff0000u; return v.f; }
__device__ __forceinline__ float b2f(u16 u) { union { u32 i; float f; } v; v.i = ((u32)u) << 16; return v.f; }
__device__ __forceinline__ u16 f2b(float f) {
    u32 x = __float_as_uint(f);
    return (u16)((x + 0x7fffu + ((x >> 16) & 1u)) >> 16);
}
__device__ __forceinline__ u32 pk2(float lo, float hi) {
    return ((u32)f2b(hi) << 16) | (u32)f2b(lo);
}
__device__ __forceinline__ bf16x8 pack8(float4 a, float4 b) {
    union { u32 u[4]; bf16x8 v; } r;
    r.u[0] = pk2(a.x, a.y); r.u[1] = pk2(a.z, a.w);
    r.u[2] = pk2(b.x, b.y); r.u[3] = pk2(b.z, b.w);
    return r.v;
}

// ---------------------------------------------------------------------------
// Kernel 0: weight prep. Wt[mat][n][c] bf16 = W[c][n],
// mat = {Wq*LOG2E/sqrt(D), Wk, Wv, Wo, Wg}; WbT[h][c] = Wbias[c][h]*LOG2E.
// ---------------------------------------------------------------------------
__global__ __launch_bounds__(256) void k_prep(
    const float* __restrict__ Wq, const float* __restrict__ Wk, const float* __restrict__ Wv,
    const float* __restrict__ Wo, const float* __restrict__ Wg,
    const float* __restrict__ Wbias, u16* __restrict__ Wt, float* __restrict__ WbT)
{
    __shared__ float tile[64][65];
    const int b = blockIdx.x, t = threadIdx.x;
    if (b < 20) {
        const int mat = b >> 2, tl = b & 3, tr = tl >> 1, tc = tl & 1;
        const float* W = (mat == 0) ? Wq : (mat == 1) ? Wk : (mat == 2) ? Wv : (mat == 3) ? Wo : Wg;
        const float s = (mat == 0) ? 0.2550680544705824f : 1.f;   // LOG2E/sqrt(32)
        const int rlo = t >> 6, col = t & 63;
        #pragma unroll
        for (int m = 0; m < 16; ++m) {
            int row = m * 4 + rlo;
            tile[row][col] = W[(size_t)(tr * 64 + row) * C_ + tc * 64 + col];
        }
        __syncthreads();
        #pragma unroll
        for (int m = 0; m < 16; ++m) {
            int n = tc * 64 + m * 4 + rlo;
            int c = tr * 64 + col;
            Wt[mat * 16384 + n * C_ + c] = f2b(tile[col][m * 4 + rlo] * s);
        }
    } else {
        #pragma unroll
        for (int m = 0; m < 2; ++m) {
            int idx = m * 256 + t;
            int h = idx >> 7, c = idx & 127;
            WbT[h * C_ + c] = Wbias[c * H_ + h] * 1.4426950408889634f;
        }
    }
}

// ---------------------------------------------------------------------------
// Kernel 1: LayerNorm + Q/K/V + bias projection. REVERTED to the round-3/9
// 64-row body (proven 52 us). Two pipelining attempts (rounds 10/11) both
// lost: round-10 to pointer-decay scratch spills, round-11 to the extra
// barriers/smaller chunks (+11 us). 52 us is this structure's floor.
// biasN bf16 natural [h][j][k], LOG2E-prescaled.
// ---------------------------------------------------------------------------
__global__ __launch_bounds__(256) void k_lnmm(
    const float* __restrict__ pair, const float* __restrict__ ln_g, const float* __restrict__ ln_b,
    const u16* __restrict__ Wt, const float* __restrict__ WbT,
    u16* __restrict__ qh, u16* __restrict__ kh, u16* __restrict__ vh,
    u16* __restrict__ biasN)
{
    __shared__ u16 zsh[64][136];

    const int t  = threadIdx.x;
    const int p0 = blockIdx.x * 64;
    const int row = t >> 2, seg = t & 3;

    float4 xv[8];
    float sum = 0.f, ss = 0.f;
    #pragma unroll
    for (int i = 0; i < 8; ++i) {
        int c = (seg + 4 * i) * 4;
        float4 x = *(const float4*)(pair + (size_t)(p0 + row) * C_ + c);
        xv[i] = x;
        sum += x.x + x.y + x.z + x.w;
        ss  += x.x * x.x + x.y * x.y + x.z * x.z + x.w * x.w;
    }
    sum += __shfl_xor(sum, 1); sum += __shfl_xor(sum, 2);
    ss  += __shfl_xor(ss, 1);  ss  += __shfl_xor(ss, 2);
    float mu  = sum * (1.0f / C_);
    float var = ss * (1.0f / C_) - mu * mu;
    float rs  = rsqrtf(fmaxf(var, 0.f) + 1e-5f);

    #pragma unroll
    for (int i = 0; i < 8; ++i) {
        int c = (seg + 4 * i) * 4;
        float4 g4 = *(const float4*)(ln_g + c);
        float4 b4 = *(const float4*)(ln_b + c);
        float4 x  = xv[i];
        float z0 = (x.x - mu) * rs * g4.x + b4.x;
        float z1 = (x.y - mu) * rs * g4.y + b4.y;
        float z2 = (x.z - mu) * rs * g4.z + b4.z;
        float z3 = (x.w - mu) * rs * g4.w + b4.w;
        *(u32*)&zsh[row][c]     = pk2(z0, z1);
        *(u32*)&zsh[row][c + 2] = pk2(z2, z3);
    }
    __syncthreads();

    const int w    = t >> 6;
    const int l15  = t & 15;
    const int quad = (t >> 4) & 3;

    bf16x8 zf[4][4];
    #pragma unroll
    for (int jt = 0; jt < 4; ++jt)
        #pragma unroll
        for (int kc = 0; kc < 4; ++kc)
            zf[jt][kc] = *(const bf16x8*)&zsh[jt * 16 + l15][kc * 32 + quad * 8];

    #pragma unroll
    for (int k = 0; k < 6; ++k) {
        const int tt = w * 6 + k;
        const int mat = tt >> 3, mt = tt & 7;
        f32x4 acc0 = {0.f,0.f,0.f,0.f}, acc1 = acc0, acc2 = acc0, acc3 = acc0;
        #pragma unroll
        for (int kc = 0; kc < 4; ++kc) {
            bf16x8 af = *(const bf16x8*)(Wt + (size_t)tt * 2048 + (size_t)l15 * 128 + kc * 32 + quad * 8);
            acc0 = __builtin_amdgcn_mfma_f32_16x16x32_bf16(af, zf[0][kc], acc0, 0, 0, 0);
            acc1 = __builtin_amdgcn_mfma_f32_16x16x32_bf16(af, zf[1][kc], acc1, 0, 0, 0);
            acc2 = __builtin_amdgcn_mfma_f32_16x16x32_bf16(af, zf[2][kc], acc2, 0, 0, 0);
            acc3 = __builtin_amdgcn_mfma_f32_16x16x32_bf16(af, zf[3][kc], acc3, 0, 0, 0);
        }
        u16* dst = (mat == 0) ? qh : (mat == 1) ? kh : vh;
        const int hh = mt >> 1;
        const int cb = (mt & 1) * 16 + quad * 4;
        f32x4 accs[4] = {acc0, acc1, acc2, acc3};
        #pragma unroll
        for (int jt = 0; jt < 4; ++jt) {
            const int p = p0 + jt * 16 + l15;
            *(uint2*)(dst + ((size_t)hh * NP_ + p) * D_ + cb) =
                make_uint2(pk2(accs[jt][0], accs[jt][1]), pk2(accs[jt][2], accs[jt][3]));
        }
    }

    {
        float a = 0.f;
        #pragma unroll
        for (int c8 = 0; c8 < C_; c8 += 8) {
            uint4 zz = *(const uint4*)&zsh[row][c8];
            float4 wb0 = *(const float4*)(WbT + seg * C_ + c8);
            float4 wb1 = *(const float4*)(WbT + seg * C_ + c8 + 4);
            a += bflo(zz.x) * wb0.x + bfhi(zz.x) * wb0.y
               + bflo(zz.y) * wb0.z + bfhi(zz.y) * wb0.w
               + bflo(zz.z) * wb1.x + bfhi(zz.z) * wb1.y
               + bflo(zz.w) * wb1.z + bfhi(zz.w) * wb1.w;
        }
        const int p = p0 + row;
        biasN[(size_t)seg * NP_ + p] = f2b(a);    // bf16, LOG2E-prescaled
    }
}

// ---------------------------------------------------------------------------
// Kernel 2: attention + output projection merged. Round-12 change: the
// per-wave P buffer is PING-PONGED across jt (slot = jt&1). Previously one
// slot was rewritten every jt iteration -> lgkmcnt-ordered WAR serialized
// the 4 jt chains (defeating the designed ILP; MfmaUtil stuck at 8%).
// No LDS headroom for 2x Psh alongside everything, but ao_sh (69.6 KB) is
// dead during the kc loop and Psh is dead after it -> alias the 2 slots into
// ao_sh's base, and add ONE barrier between the kc loop and the ao_sh
// epilogue so no wave's ao writes can land in another wave's live P slot.
// Psh leaves shA -> shA shrinks to 69632 (out-phase W staging still fits);
// LDS total 157696 -> 139264.
// ---------------------------------------------------------------------------
__global__ __launch_bounds__(1024)
__attribute__((amdgpu_waves_per_eu(4, 4)))
void k_ao(
    const u16* __restrict__ qh, const u16* __restrict__ kh, const u16* __restrict__ vh,
    const u16* __restrict__ biasN, const float* __restrict__ pair,
    const u16* __restrict__ Wt, const float* __restrict__ bo,
    const float* __restrict__ bg, float* __restrict__ out)
{
    __shared__ __align__(16) char shA[69632];   // attn: Vsh(67584); out: WoSh+WgSh
    __shared__ u16 ao_sh[256 * 136];            // attn: P ping-pong slots; out: ao

    u16* Vsh = reinterpret_cast<u16*>(shA);     // 4*32*264 u16 = 67584 B

    const int t = threadIdx.x;
    const int i = blockIdx.x;
    const int wave = t >> 6;              // 0..15
    const int h    = wave >> 2;           // head 0..3
    const int ww   = wave & 3;            // j-quarter
    const int l15  = t & 15;
    const int quad = (t >> 4) & 3;
    const int jbase = ww * 64;

    // P ping-pong: 2 slots x [16][40] u16 per wave, aliased into ao_sh.
    u16* P0 = ao_sh + wave * 1280;        // slot 0
    u16* P1 = P0 + 640;                   // slot 1   (16 waves x 1280 = 20480 u16)

    const u16* Kg = kh + ((size_t)h * NP_ + i * L_) * D_;
    const u16* Qg = qh + ((size_t)h * NP_ + i * L_) * D_;

    // ---- stage V transposed for ALL 4 heads ----
    #pragma unroll
    for (int jj = 0; jj < 4; ++jj) {
        int idx = t + jj * 1024;
        int hs = idx >> 10, rem = idx & 1023;
        int r = rem >> 2, sg = rem & 3;
        const u16* Vg = vh + ((size_t)hs * NP_ + i * L_) * D_;
        union { uint4 q; u16 s[8]; } u;
        u.q = *(const uint4*)(Vg + r * D_ + sg * 8);
        #pragma unroll
        for (int m = 0; m < 8; ++m) Vsh[hs * 8448 + (sg * 8 + m) * 264 + r] = u.s[m];
    }

    // ---- Q B-frags (4 j-tiles per wave) ----
    bf16x8 qf[4];
    #pragma unroll
    for (int jt = 0; jt < 4; ++jt)
        qf[jt] = *(const bf16x8*)(Qg + (size_t)(jbase + jt * 16 + l15) * D_ + quad * 8);

    __syncthreads();

    const f32x4 z4 = {0.f, 0.f, 0.f, 0.f};
    f32x4 oacc[4][2], osum[4];
    #pragma unroll
    for (int jt = 0; jt < 4; ++jt) {
        oacc[jt][0] = z4; oacc[jt][1] = z4; osum[jt] = z4;
    }

    bf16x8 onesb;
    { union { u32 u[4]; bf16x8 v; } ob;
      ob.u[0] = ob.u[1] = ob.u[2] = ob.u[3] = 0x3F803F80u; onesb = ob.v; }

    const u16* bN = biasN + (size_t)h * NP_;   // [j][k] bf16, LOG2E-scaled
    const u16* Vs = Vsh + h * 8448;

    bf16x8 kb0 = *(const bf16x8*)(Kg + (size_t)l15 * D_ + quad * 8);
    bf16x8 kb1 = *(const bf16x8*)(Kg + (size_t)(16 + l15) * D_ + quad * 8);

    for (int kc = 0; kc < 8; ++kc) {
        bf16x8 nb0, nb1;
        if (kc < 7) {
            nb0 = *(const bf16x8*)(Kg + (size_t)((kc + 1) * 32 + l15) * D_ + quad * 8);
            nb1 = *(const bf16x8*)(Kg + (size_t)((kc + 1) * 32 + 16 + l15) * D_ + quad * 8);
        }
        bf16x8 vb0 = *(const bf16x8*)&Vs[l15 * 264 + kc * 32 + quad * 8];
        bf16x8 vb1 = *(const bf16x8*)&Vs[(16 + l15) * 264 + kc * 32 + quad * 8];

        #pragma unroll
        for (int jt = 0; jt < 4; ++jt) {
            u16* P = (jt & 1) ? P1 : P0;   // compile-time slot select (unrolled)

            f32x4 s0 = __builtin_amdgcn_mfma_f32_16x16x32_bf16(kb0, qf[jt], z4, 0, 0, 0);
            f32x4 s1 = __builtin_amdgcn_mfma_f32_16x16x32_bf16(kb1, qf[jt], z4, 0, 0, 0);

            const u16* bp = bN + (size_t)(jbase + jt * 16 + l15) * L_ + kc * 32 + quad * 4;
            uint2 bv0 = *(const uint2*)bp;          // bias[j][k..k+3] bf16
            uint2 bv1 = *(const uint2*)(bp + 16);   // bias[j][k+16..k+19]
            const u16* b0p = (const u16*)&bv0;
            const u16* b1p = (const u16*)&bv1;

            float e0[4], e1[4];
            #pragma unroll
            for (int r = 0; r < 4; ++r) {
                e0[r] = __builtin_amdgcn_exp2f(s0[r] + b2f(b0p[r]));
                e1[r] = __builtin_amdgcn_exp2f(s1[r] + b2f(b1p[r]));
            }

            u32 w0, w1, w2, w3;
            asm("v_cvt_pk_bf16_f32 %0, %1, %2" : "=v"(w0) : "v"(e0[0]), "v"(e0[1]));
            asm("v_cvt_pk_bf16_f32 %0, %1, %2" : "=v"(w1) : "v"(e0[2]), "v"(e0[3]));
            asm("v_cvt_pk_bf16_f32 %0, %1, %2" : "=v"(w2) : "v"(e1[0]), "v"(e1[1]));
            asm("v_cvt_pk_bf16_f32 %0, %1, %2" : "=v"(w3) : "v"(e1[2]), "v"(e1[3]));
            *(uint2*)&P[l15 * 40 + quad * 4]      = make_uint2(w0, w1);
            *(uint2*)&P[l15 * 40 + 16 + quad * 4] = make_uint2(w2, w3);

            bf16x8 pa = *(const bf16x8*)&P[l15 * 40 + quad * 8];
            oacc[jt][0] = __builtin_amdgcn_mfma_f32_16x16x32_bf16(pa, vb0,   oacc[jt][0], 0, 0, 0);
            oacc[jt][1] = __builtin_amdgcn_mfma_f32_16x16x32_bf16(pa, vb1,   oacc[jt][1], 0, 0, 0);
            osum[jt]    = __builtin_amdgcn_mfma_f32_16x16x32_bf16(pa, onesb, osum[jt],    0, 0, 0);
        }
        kb0 = nb0; kb1 = nb1;
    }

    __syncthreads();   // ALL waves done with P slots before any ao_sh write

    // ---- normalize + write to LDS ao_sh[row][h*32 + d] ----
    #pragma unroll
    for (int jt = 0; jt < 4; ++jt) {
        #pragma unroll
        for (int r = 0; r < 4; ++r) {
            float rn = 1.f / osum[jt][r];
            int prow = jbase + jt * 16 + quad * 4 + r;          // 0..255
            ao_sh[prow * 136 + h * 32 + l15]      = f2b(oacc[jt][0][r] * rn);
            ao_sh[prow * 136 + h * 32 + 16 + l15] = f2b(oacc[jt][1][r] * rn);
        }
    }

    __syncthreads();   // ao_sh complete; Vsh dead

    // ---- stage Wo/Wg into the dead attn region, pad-136 stride ----
    u16* WoSh = reinterpret_cast<u16*>(shA);            // [128][136]
    u16* WgSh = WoSh + 128 * 136;                       // [128][136]
    {
        const u16* WoT = Wt + 3 * 16384;
        const u16* WgT = Wt + 4 * 16384;
        #pragma unroll
        for (int m = 0; m < 2; ++m) {
            int idx = t + m * 1024;
            int rw = idx >> 4, cl = (idx & 15) * 8;
            *(uint4*)&WoSh[rw * 136 + cl] = *(const uint4*)(WoT + rw * 128 + cl);
            *(uint4*)&WgSh[rw * 136 + cl] = *(const uint4*)(WgT + rw * 128 + cl);
        }
    }
    __syncthreads();

    // ================= out phase: wave owns 16 rows =================
    const int prow_l = wave * 16 + l15;          // local row 0..255
    const int pg     = i * L_ + prow_l;          // global pair row

    bf16x8 aof[4], pf[4];
    #pragma unroll
    for (int kc = 0; kc < 4; ++kc) {
        aof[kc] = *(const bf16x8*)&ao_sh[prow_l * 136 + kc * 32 + quad * 8];
        const float* pp = pair + (size_t)pg * C_ + kc * 32 + quad * 8;
        pf[kc] = pack8(*(const float4*)pp, *(const float4*)(pp + 4));
    }

    #pragma unroll
    for (int nt = 0; nt < 8; ++nt) {
        f32x4 accO = {0.f,0.f,0.f,0.f}, accG = accO;
        #pragma unroll
        for (int kc = 0; kc < 4; ++kc) {
            bf16x8 awo = *(const bf16x8*)&WoSh[(nt * 16 + l15) * 136 + kc * 32 + quad * 8];
            bf16x8 awg = *(const bf16x8*)&WgSh[(nt * 16 + l15) * 136 + kc * 32 + quad * 8];
            accO = __builtin_amdgcn_mfma_f32_16x16x32_bf16(awo, aof[kc], accO, 0, 0, 0);
            accG = __builtin_amdgcn_mfma_f32_16x16x32_bf16(awg, pf[kc],  accG, 0, 0, 0);
        }
        const int ch = nt * 16 + quad * 4;
        float4 bo4 = *(const float4*)(bo + ch);
        float4 bg4 = *(const float4*)(bg + ch);
        float4 pr  = *(const float4*)(pair + (size_t)pg * C_ + ch);
        float4 r;
        r.x = pr.x + (1.f / (1.f + __expf(-(accG[0] + bg4.x)))) * (accO[0] + bo4.x);
        r.y = pr.y + (1.f / (1.f + __expf(-(accG[1] + bg4.y)))) * (accO[1] + bo4.y);
        r.z = pr.z + (1.f / (1.f + __expf(-(accG[2] + bg4.z)))) * (accO[2] + bo4.z);
        r.w = pr.w + (1.f / (1.f + __expf(-(accG[3] + bg4.w)))) * (accO[3] + bo4.w);
        *(float4*)(out + (size_t)pg * C_ + ch) = r;
    }
}

// ---------------------------------------------------------------------------
// Workspace (~51 MB):
//   [0, 0.5 MB)    biasN bf16 [H][j][k]   (natural layout, LOG2E-prescaled)
//   [+,  +16.8MB)  qh bf16 [H][NP][32]
//   [+,  +16.8MB)  kh
//   [+,  +16.8MB)  vh
//   [+,  +160K)    Wt bf16 [5][128][128]
//   [+,  +2K)      WbT fp32 [4][128]
// ---------------------------------------------------------------------------
extern "C" void kernel_launch(void* const* d_in, const int* in_sizes, int n_in,
                              void* d_out, int out_size, void* d_ws, size_t ws_size,
                              hipStream_t stream) {
    const float* pair  = (const float*)d_in[0];
    const float* ln_g  = (const float*)d_in[1];
    const float* ln_b  = (const float*)d_in[2];
    const float* Wq    = (const float*)d_in[3];
    const float* Wk    = (const float*)d_in[4];
    const float* Wv    = (const float*)d_in[5];
    const float* Wbias = (const float*)d_in[6];
    const float* Wo    = (const float*)d_in[7];
    const float* bo    = (const float*)d_in[8];
    const float* Wg    = (const float*)d_in[9];
    const float* bg    = (const float*)d_in[10];
    float* out = (float*)d_out;

    u16* biasN = (u16*)d_ws;                          // 0.5 MB bf16
    u16* qh = biasN + (size_t)H_ * NP_;
    u16* kh = qh + (size_t)NP_ * C_;
    u16* vh = kh + (size_t)NP_ * C_;
    u16* Wt = vh + (size_t)NP_ * C_;
    float* WbT = (float*)(Wt + 5 * 16384);

    k_prep<<<21, 256, 0, stream>>>(Wq, Wk, Wv, Wo, Wg, Wbias, Wt, WbT);
    k_lnmm<<<NP_ / 64, 256, 0, stream>>>(pair, ln_g, ln_b, Wt, WbT, qh, kh, vh, biasN);
    k_ao<<<L_, 1024, 0, stream>>>(qh, kh, vh, biasN, pair, Wt, bo, bg, out);
}